// Round 4
// baseline (1247.386 us; speedup 1.0000x reference)
//
#include <hip/hip_runtime.h>
#include <hip/hip_bf16.h>

// C[m,n] = sum_{r,k} A[r][m][k] * B[r][n][k]
// Phase 1: convert A,B -> bf16 in d_ws (K contiguous: k' = r*1024+k).
// Phase 2: 256x256 GEMM, 32x32x16 MFMA, one-phase-ahead ds_read pipeline,
//          counted lgkmcnt + counted vmcnt, T2 swizzle, T5 setprio.

#define M_TOT 8192
#define N_TOT 4096
#define LK    1024
#define NR    8
#define K_TOT (NR * LK)    // 8192
#define NT    (K_TOT / 64) // 128 K-tiles

typedef float f32x4  __attribute__((ext_vector_type(4)));
typedef float f32x16 __attribute__((ext_vector_type(16)));
typedef short s16x8  __attribute__((ext_vector_type(8)));
typedef const __attribute__((address_space(1))) unsigned int* gptr_t;
typedef __attribute__((address_space(3))) unsigned int* lptr_t;

__device__ inline short f2bf(float f) {
    __hip_bfloat16 h = __float2bfloat16(f);
    return *reinterpret_cast<short*>(&h);
}

// ---------------- convert pre-pass ----------------
__global__ __launch_bounds__(256)
void cvt_bf16(const float* __restrict__ in, short* __restrict__ out,
              int row_shift, int row_mask) {
    const int row = blockIdx.x * 2 + (threadIdx.x >> 7);
    const int c   = (threadIdx.x & 127) * 8;
    const int r   = row >> row_shift;
    const int m   = row & row_mask;
    const float* src = in + ((size_t)row << 10) + c;
    f32x4 v0 = *(const f32x4*)src;
    f32x4 v1 = *(const f32x4*)(src + 4);
    s16x8 o;
    #pragma unroll
    for (int j = 0; j < 4; ++j) { o[j] = f2bf(v0[j]); o[j + 4] = f2bf(v1[j]); }
    *(s16x8*)(out + ((size_t)m << 13) + ((size_t)r << 10) + c) = o;
}

// ---------------- GEMM helpers ----------------
// LDS: buf P at P*32768 shorts; A-tile [256][64] at +0, B-tile at +16384.
// Swizzle: LDS granule g of row r holds global granule g ^ (r&7).

__device__ __forceinline__ void stage_half(const short* srcBase, short* ldsOp,
                                           int half, int ktile, int wid) {
    #pragma unroll
    for (int q = 0; q < 2; ++q) {
        const short* src = srcBase + (size_t)(half * 128 + q * 8) * K_TOT + ktile * 64;
        short* dst = ldsOp + (half * 128 + wid * 16 + q * 8) * 64;  // wave-uniform
        __builtin_amdgcn_global_load_lds((gptr_t)src, (lptr_t)dst, 16, 0, 0);
    }
}

__device__ __forceinline__ s16x8 read_frag(const short* base, int row, int gk) {
    return *(const s16x8*)(base + row * 64 + ((gk ^ (row & 7)) << 3));
}

// A fragments: cluster C -> rows (2C+wm)*32 .. +31 (interleaved m-frag mapping)
template<int C>
__device__ __forceinline__ void read_a_cluster(s16x8 (&afr)[4][4], const short* lAc,
                                               int wm, int c31, int kh) {
    #pragma unroll
    for (int ks = 0; ks < 4; ++ks)
        afr[C][ks] = read_frag(lAc, (2 * C + wm) * 32 + c31, ks * 2 + kh);
}

template<int PB>
__device__ __forceinline__ void read_b_all(s16x8 (&bfr)[2][2][4], const short* lBc,
                                           int wn, int c31, int kh) {
    #pragma unroll
    for (int nf = 0; nf < 2; ++nf)
        #pragma unroll
        for (int ks = 0; ks < 4; ++ks)
            bfr[PB][nf][ks] = read_frag(lBc, wn * 64 + nf * 32 + c31, ks * 2 + kh);
}

template<int C, int PB>
__device__ __forceinline__ void mfma_cluster(f32x16 (&acc)[4][2], s16x8 (&afr)[4][4],
                                             s16x8 (&bfr)[2][2][4]) {
    __builtin_amdgcn_s_setprio(1);
    #pragma unroll
    for (int nf = 0; nf < 2; ++nf)
        #pragma unroll
        for (int ks = 0; ks < 4; ++ks)
            acc[C][nf] = __builtin_amdgcn_mfma_f32_32x32x16_bf16(
                afr[C][ks], bfr[PB][nf][ks], acc[C][nf], 0, 0, 0);
    __builtin_amdgcn_s_setprio(0);
}

#define MEMCLOB asm volatile("" ::: "memory")
#define BAR     __builtin_amdgcn_s_barrier()
#define SCHED0  __builtin_amdgcn_sched_barrier(0)

// One K-tile, parity P (compile-time 0/1). Reads for cluster c+1 issued before
// MFMA c; next tile's B + c0 reads issued at p4 after vmcnt+barrier.
#define TILE_BODY(P) do {                                                     \
    const int t = 2 * t2 + (P);                                               \
    const short* lAc = smem + ((P) << 15);                                    \
    short* bufN = smem + (((P) ^ 1) << 15);                                   \
    short* bufC = smem + ((P) << 15);                                         \
    /* phase 1 */                                                             \
    read_a_cluster<1>(afr, lAc, wm, c31, kh);                                 \
    if (t + 1 < NT) stage_half(srcA, bufN, 1, t + 1, wid);                    \
    MEMCLOB; BAR;                                                             \
    asm volatile("s_waitcnt lgkmcnt(4)" ::: "memory"); SCHED0;                \
    mfma_cluster<0, (P)>(acc, afr, bfr);                                      \
    MEMCLOB; BAR;                                                             \
    /* phase 2 */                                                             \
    read_a_cluster<2>(afr, lAc, wm, c31, kh);                                 \
    if (t + 2 < NT) stage_half(srcB, bufC + 16384, 0, t + 2, wid);            \
    MEMCLOB; BAR;                                                             \
    asm volatile("s_waitcnt lgkmcnt(4)" ::: "memory"); SCHED0;                \
    mfma_cluster<1, (P)>(acc, afr, bfr);                                      \
    MEMCLOB; BAR;                                                             \
    /* phase 3 */                                                             \
    read_a_cluster<3>(afr, lAc, wm, c31, kh);                                 \
    if (t + 2 < NT) stage_half(srcB, bufC + 16384, 1, t + 2, wid);            \
    MEMCLOB; BAR;                                                             \
    asm volatile("s_waitcnt lgkmcnt(4)" ::: "memory"); SCHED0;                \
    mfma_cluster<2, (P)>(acc, afr, bfr);                                      \
    MEMCLOB; BAR;                                                             \
    /* phase 4: drain own reads, confirm next tile staged (cross-wave via    */\
    /* barrier), then hoist next tile's B + c0 reads under MFMA c3.          */\
    asm volatile("s_waitcnt lgkmcnt(0)" ::: "memory");                        \
    if (t < NT - 2)       asm volatile("s_waitcnt vmcnt(4)" ::: "memory");    \
    else if (t == NT - 2) asm volatile("s_waitcnt vmcnt(0)" ::: "memory");    \
    MEMCLOB; BAR;                                                             \
    if (t + 1 < NT) {                                                         \
        read_b_all<((P) ^ 1)>(bfr, bufN + 16384, wn, c31, kh);                \
        read_a_cluster<0>(afr, bufN, wm, c31, kh);                            \
    }                                                                         \
    if (t + 2 < NT) stage_half(srcA, bufC, 0, t + 2, wid);                    \
    SCHED0;                                                                   \
    mfma_cluster<3, (P)>(acc, afr, bfr);                                      \
    MEMCLOB; BAR;                                                             \
} while (0)

__global__ __launch_bounds__(512, 2)
void gemm8(const short* __restrict__ A, const short* __restrict__ B,
           float* __restrict__ C) {
    extern __shared__ short smem[];

    const int tid  = threadIdx.x;
    const int lane = tid & 63;
    const int wid  = tid >> 6;
    const int wm   = wid >> 2;      // 0..1
    const int wn   = wid & 3;       // 0..3
    const int c31  = lane & 31;
    const int kh   = lane >> 5;     // 0..1
    const int l8   = lane >> 3;     // 0..7
    const int g16  = (lane & 7) ^ l8;  // pre-swizzled source granule

    const int bid = blockIdx.x;
    const int sw  = (bid & 7) * 64 + (bid >> 3);   // bijective (512 % 8 == 0)
    const int bm  = sw >> 4;   // 0..31
    const int bn  = sw & 15;   // 0..15

    const short* srcA = A + (size_t)(bm * 256 + wid * 16 + l8) * K_TOT + g16 * 8;
    const short* srcB = B + (size_t)(bn * 256 + wid * 16 + l8) * K_TOT + g16 * 8;

    // Prologue: tile0 fully + tile1 {B0,B1,A0} (A1(t=1) staged at iter0 p1)
    stage_half(srcB, smem + 16384, 0, 0, wid);
    stage_half(srcB, smem + 16384, 1, 0, wid);
    stage_half(srcA, smem,         0, 0, wid);
    stage_half(srcA, smem,         1, 0, wid);
    stage_half(srcB, smem + 49152, 0, 1, wid);
    stage_half(srcB, smem + 49152, 1, 1, wid);
    stage_half(srcA, smem + 32768, 0, 1, wid);
    asm volatile("s_waitcnt vmcnt(6)" ::: "memory");  // tile0's 8 loads done
    MEMCLOB; BAR;

    f32x16 acc[4][2];
    #pragma unroll
    for (int f = 0; f < 4; ++f)
        #pragma unroll
        for (int n = 0; n < 2; ++n)
            #pragma unroll
            for (int e = 0; e < 16; ++e)
                acc[f][n][e] = 0.f;

    s16x8 afr[4][4];
    s16x8 bfr[2][2][4];

    // steady-state entry: tile0's B + c0 reads in flight
    read_b_all<0>(bfr, smem + 16384, wn, c31, kh);
    read_a_cluster<0>(afr, smem, wm, c31, kh);

    for (int t2 = 0; t2 < NT / 2; ++t2) {
        TILE_BODY(0);
        TILE_BODY(1);
    }

    // Epilogue: 32x32 C/D layout col=lane&31, row=(reg&3)+8*(reg>>2)+4*(lane>>5)
    // global row = bm*256 + (2*mf+wm)*32 + 4*kh + (reg&3) + 8*(reg>>2)
    float* Cp = C + (size_t)(bm * 256 + wm * 32 + 4 * kh) * N_TOT
                  + bn * 256 + wn * 64 + c31;
    #pragma unroll
    for (int mf = 0; mf < 4; ++mf)
        #pragma unroll
        for (int nf = 0; nf < 2; ++nf)
            #pragma unroll
            for (int reg = 0; reg < 16; ++reg) {
                const int roff = mf * 64 + (reg & 3) + 8 * (reg >> 2);
                Cp[(size_t)roff * N_TOT + nf * 32] = acc[mf][nf][reg];
            }
}

// ---------------- fallback (only if ws too small) ----------------
#define PAD_ROW 40
__global__ __launch_bounds__(256, 2)
void gemm_rs_fused(const float* __restrict__ A, const float* __restrict__ B,
                   float* __restrict__ C) {
    __shared__ short lA[128 * PAD_ROW];
    __shared__ short lB[128 * PAD_ROW];
    const int bid = blockIdx.x;
    const int sw  = (bid & 7) * (int)(gridDim.x >> 3) + (bid >> 3);
    const int bm = sw >> 5, bn = sw & 31;
    const int tid = threadIdx.x, lane = tid & 63, wid = tid >> 6;
    const int wr = wid >> 1, wc = wid & 1, r15 = lane & 15, kg = lane >> 4;
    const int srow = tid >> 1, scg = tid & 1;
    const float* gA = A + ((size_t)(bm * 128 + srow) << 10) + scg * 16;
    const float* gB = B + ((size_t)(bn * 128 + srow) << 10) + scg * 16;
    short* wpA = lA + srow * PAD_ROW + scg * 16;
    short* wpB = lB + srow * PAD_ROW + scg * 16;
    const short* rpA = lA + (wr * 64 + r15) * PAD_ROW + kg * 8;
    const short* rpB = lB + (wc * 64 + r15) * PAD_ROW + kg * 8;
    f32x4 acc[4][4];
    #pragma unroll
    for (int i = 0; i < 4; ++i)
        #pragma unroll
        for (int j = 0; j < 4; ++j) acc[i][j] = (f32x4){0.f, 0.f, 0.f, 0.f};
    for (int t = 0; t < K_TOT / 32; ++t) {
        const int r = t >> 5, k0 = (t & 31) << 5;
        const float* pA = gA + (size_t)r * (M_TOT * LK) + k0;
        const float* pB = gB + (size_t)r * (N_TOT * LK) + k0;
        f32x4 va[4], vb[4];
        #pragma unroll
        for (int q = 0; q < 4; ++q) va[q] = *(const f32x4*)(pA + q * 4);
        #pragma unroll
        for (int q = 0; q < 4; ++q) vb[q] = *(const f32x4*)(pB + q * 4);
        __syncthreads();
        s16x8 oa0, oa1, ob0, ob1;
        #pragma unroll
        for (int q = 0; q < 2; ++q)
            #pragma unroll
            for (int i = 0; i < 4; ++i) {
                oa0[q * 4 + i] = f2bf(va[q][i]);
                oa1[q * 4 + i] = f2bf(va[q + 2][i]);
                ob0[q * 4 + i] = f2bf(vb[q][i]);
                ob1[q * 4 + i] = f2bf(vb[q + 2][i]);
            }
        *(s16x8*)(wpA) = oa0; *(s16x8*)(wpA + 8) = oa1;
        *(s16x8*)(wpB) = ob0; *(s16x8*)(wpB + 8) = ob1;
        __syncthreads();
        s16x8 af[4], bfr2[4];
        #pragma unroll
        for (int i = 0; i < 4; ++i) af[i]   = *(const s16x8*)(rpA + i * 16 * PAD_ROW);
        #pragma unroll
        for (int i = 0; i < 4; ++i) bfr2[i] = *(const s16x8*)(rpB + i * 16 * PAD_ROW);
        #pragma unroll
        for (int i = 0; i < 4; ++i)
            #pragma unroll
            for (int j = 0; j < 4; ++j)
                acc[i][j] = __builtin_amdgcn_mfma_f32_16x16x32_bf16(
                    af[i], bfr2[j], acc[i][j], 0, 0, 0);
    }
    float* Cp = C + (size_t)(bm * 128 + wr * 64 + kg * 4) * N_TOT
                  + bn * 128 + wc * 64 + r15;
    #pragma unroll
    for (int i = 0; i < 4; ++i)
        #pragma unroll
        for (int j = 0; j < 4; ++j)
            #pragma unroll
            for (int jj = 0; jj < 4; ++jj)
                Cp[(size_t)(i * 16 + jj) * N_TOT + j * 16] = acc[i][j][jj];
}

extern "C" void kernel_launch(void* const* d_in, const int* in_sizes, int n_in,
                              void* d_out, int out_size, void* d_ws, size_t ws_size,
                              hipStream_t stream) {
    const float* A = (const float*)d_in[0];   // [8, 8192, 1024]
    const float* B = (const float*)d_in[1];   // [8, 4096, 1024]
    float* C = (float*)d_out;                 // [8192, 4096]

    const size_t needA = (size_t)M_TOT * K_TOT * 2;
    const size_t needB = (size_t)N_TOT * K_TOT * 2;

    if (ws_size >= needA + needB) {
        short* Abf = (short*)d_ws;
        short* Bbf = (short*)((char*)d_ws + needA);
        cvt_bf16<<<dim3(NR * M_TOT / 2), dim3(256), 0, stream>>>(A, Abf, 13, 8191);
        cvt_bf16<<<dim3(NR * N_TOT / 2), dim3(256), 0, stream>>>(B, Bbf, 12, 4095);
        gemm8<<<dim3((M_TOT / 256) * (N_TOT / 256)), dim3(512), 131072, stream>>>(Abf, Bbf, C);
    } else {
        gemm_rs_fused<<<dim3((M_TOT / 128) * (N_TOT / 128)), dim3(256), 0, stream>>>(A, B, C);
    }
}

// Round 5
// 523.365 us; speedup vs baseline: 2.3834x; 2.3834x over previous
//
#include <hip/hip_runtime.h>
#include <hip/hip_bf16.h>

// C[m,n] = sum_{r,k} A[r][m][k] * B[r][n][k]
// Phase 1: convert A,B -> bf16 in d_ws (K contiguous: k' = r*1024+k).
// Phase 2: 256x256 GEMM, 16x16x32 MFMA (r3's conflict-free fragment pattern),
//          one-cluster-ahead ds_read pipeline with counted lgkmcnt,
//          counted vmcnt staging, T2 swizzle, T5 setprio.
// r4 lesson: no double-buffered B-fragments (register budget 256/wave);
//            next-tile reads go AFTER mfma c3 in program order instead.

#define M_TOT 8192
#define N_TOT 4096
#define LK    1024
#define NR    8
#define K_TOT (NR * LK)    // 8192
#define NT    (K_TOT / 64) // 128 K-tiles

typedef float f32x4 __attribute__((ext_vector_type(4)));
typedef short s16x8 __attribute__((ext_vector_type(8)));
typedef const __attribute__((address_space(1))) unsigned int* gptr_t;
typedef __attribute__((address_space(3))) unsigned int* lptr_t;

__device__ inline short f2bf(float f) {
    __hip_bfloat16 h = __float2bfloat16(f);
    return *reinterpret_cast<short*>(&h);
}

// ---------------- convert pre-pass ----------------
__global__ __launch_bounds__(256)
void cvt_bf16(const float* __restrict__ in, short* __restrict__ out,
              int row_shift, int row_mask) {
    const int row = blockIdx.x * 2 + (threadIdx.x >> 7);
    const int c   = (threadIdx.x & 127) * 8;
    const int r   = row >> row_shift;
    const int m   = row & row_mask;
    const float* src = in + ((size_t)row << 10) + c;
    f32x4 v0 = *(const f32x4*)src;
    f32x4 v1 = *(const f32x4*)(src + 4);
    s16x8 o;
    #pragma unroll
    for (int j = 0; j < 4; ++j) { o[j] = f2bf(v0[j]); o[j + 4] = f2bf(v1[j]); }
    *(s16x8*)(out + ((size_t)m << 13) + ((size_t)r << 10) + c) = o;
}

// ---------------- GEMM helpers ----------------
// LDS: buf P at P*32768 shorts; A-tile [256][64] at +0, B-tile at +16384.
// Swizzle: LDS granule g of row r holds global granule g ^ (r&7).

__device__ __forceinline__ void stage_half(const short* srcBase, short* ldsOp,
                                           int half, int ktile, int wid) {
    #pragma unroll
    for (int q = 0; q < 2; ++q) {
        const short* src = srcBase + (size_t)(half * 128 + q * 8) * K_TOT + ktile * 64;
        short* dst = ldsOp + (half * 128 + wid * 16 + q * 8) * 64;  // wave-uniform
        __builtin_amdgcn_global_load_lds((gptr_t)src, (lptr_t)dst, 16, 0, 0);
    }
}

// A cluster C: frags f=2C,2C+1 at rows C*64 + wm*32 + {0,16} + r15
// (c0/c1 in A0-half rows 0-127, c2/c3 in A1-half rows 128-255)
template<int C>
__device__ __forceinline__ void read_a_pair(s16x8 (&afr)[8][2], const short* lAc,
                                            int wm, int r15, int kg) {
    #pragma unroll
    for (int fo = 0; fo < 2; ++fo)
        #pragma unroll
        for (int ks = 0; ks < 2; ++ks) {
            const int row = C * 64 + wm * 32 + fo * 16 + r15;
            const int off = row * 64 + ((((ks << 2) | kg) ^ (row & 7)) << 3);
            afr[C * 2 + fo][ks] = *(const s16x8*)(lAc + off);
        }
}

__device__ __forceinline__ void read_b(s16x8 (&bfr)[4][2], const short* lBc,
                                       int wn, int r15, int kg) {
    #pragma unroll
    for (int n = 0; n < 4; ++n)
        #pragma unroll
        for (int ks = 0; ks < 2; ++ks) {
            const int row = wn * 64 + n * 16 + r15;
            const int off = row * 64 + ((((ks << 2) | kg) ^ (row & 7)) << 3);
            bfr[n][ks] = *(const s16x8*)(lBc + off);
        }
}

template<int Q>
__device__ __forceinline__ void mfma_quad(f32x4 (&acc)[8][4], s16x8 (&afr)[8][2],
                                          s16x8 (&bfr)[4][2]) {
    __builtin_amdgcn_s_setprio(1);
    #pragma unroll
    for (int fo = 0; fo < 2; ++fo)
        #pragma unroll
        for (int n = 0; n < 4; ++n)
            #pragma unroll
            for (int ks = 0; ks < 2; ++ks)
                acc[Q * 2 + fo][n] = __builtin_amdgcn_mfma_f32_16x16x32_bf16(
                    afr[Q * 2 + fo][ks], bfr[n][ks], acc[Q * 2 + fo][n], 0, 0, 0);
    __builtin_amdgcn_s_setprio(0);
}

#define MEMCLOB asm volatile("" ::: "memory")
#define BAR     __builtin_amdgcn_s_barrier()
#define SCHED0  __builtin_amdgcn_sched_barrier(0)

// One K-tile, parity P. Entering p1: B + c0 reads of this tile in flight
// (issued at end of previous p4). Each phase issues next cluster's A-reads,
// waits counted lgkmcnt(4) for the previous cluster, MFMAs it.
#define TILE_BODY(P) do {                                                     \
    const int t = 2 * t2 + (P);                                               \
    const short* lAc = smem + ((P) << 15);                                    \
    short* bufN = smem + (((P) ^ 1) << 15);                                   \
    short* bufC = smem + ((P) << 15);                                         \
    /* p1: issue c1; stage A1(t+1) */                                         \
    read_a_pair<1>(afr, lAc, wm, r15, kg);                                    \
    if (t + 1 < NT) stage_half(srcA, bufN, 1, t + 1, wid);                    \
    MEMCLOB; BAR;                                                             \
    asm volatile("s_waitcnt lgkmcnt(4)" ::: "memory"); SCHED0;                \
    mfma_quad<0>(acc, afr, bfr);                                              \
    MEMCLOB; BAR;                                                             \
    /* p2: issue c2; stage B0(t+2) (this tile's B reads drained at p1) */     \
    read_a_pair<2>(afr, lAc, wm, r15, kg);                                    \
    if (t + 2 < NT) stage_half(srcB, bufC + 16384, 0, t + 2, wid);            \
    MEMCLOB; BAR;                                                             \
    asm volatile("s_waitcnt lgkmcnt(4)" ::: "memory"); SCHED0;                \
    mfma_quad<1>(acc, afr, bfr);                                              \
    MEMCLOB; BAR;                                                             \
    /* p3: issue c3; stage B1(t+2) */                                         \
    read_a_pair<3>(afr, lAc, wm, r15, kg);                                    \
    if (t + 2 < NT) stage_half(srcB, bufC + 16384, 1, t + 2, wid);            \
    MEMCLOB; BAR;                                                             \
    asm volatile("s_waitcnt lgkmcnt(4)" ::: "memory"); SCHED0;                \
    mfma_quad<2>(acc, afr, bfr);                                              \
    MEMCLOB; BAR;                                                             \
    /* p4: drain own reads; counted vmcnt confirms tile t+1 fully staged     */\
    /* (cross-wave via the barrier); mfma c3; THEN next-tile B+c0 reads      */\
    /* (after c3 in program order -> single-buffered bfr is safe);           */\
    /* stage A0(t+2). vmcnt units = load instrs (2 per stage_half).          */\
    asm volatile("s_waitcnt lgkmcnt(0)" ::: "memory");                        \
    if (t < NT - 2)       asm volatile("s_waitcnt vmcnt(4)" ::: "memory");    \
    else if (t == NT - 2) asm volatile("s_waitcnt vmcnt(0)" ::: "memory");    \
    MEMCLOB; BAR; SCHED0;                                                     \
    mfma_quad<3>(acc, afr, bfr);                                              \
    if (t + 1 < NT) {                                                         \
        read_b(bfr, bufN + 16384, wn, r15, kg);                               \
        read_a_pair<0>(afr, bufN, wm, r15, kg);                               \
    }                                                                         \
    if (t + 2 < NT) stage_half(srcA, bufC, 0, t + 2, wid);                    \
    MEMCLOB; BAR;                                                             \
} while (0)

__global__ __launch_bounds__(512, 2)
void gemm8(const short* __restrict__ A, const short* __restrict__ B,
           float* __restrict__ C) {
    extern __shared__ short smem[];

    const int tid  = threadIdx.x;
    const int lane = tid & 63;
    const int wid  = tid >> 6;
    const int wm   = wid >> 2;      // 0..1
    const int wn   = wid & 3;       // 0..3
    const int r15  = lane & 15;
    const int kg   = lane >> 4;     // 0..3
    const int l8   = lane >> 3;     // 0..7
    const int g16  = (lane & 7) ^ l8;  // pre-swizzled source granule

    const int bid = blockIdx.x;
    const int sw  = (bid & 7) * 64 + (bid >> 3);   // bijective (512 % 8 == 0)
    const int bm  = sw >> 4;   // 0..31
    const int bn  = sw & 15;   // 0..15

    const short* srcA = A + (size_t)(bm * 256 + wid * 16 + l8) * K_TOT + g16 * 8;
    const short* srcB = B + (size_t)(bn * 256 + wid * 16 + l8) * K_TOT + g16 * 8;

    // Prologue: tile0 complete + tile1 {B0,B1,A0} = 14 load instrs.
    stage_half(srcB, smem + 16384, 0, 0, wid);
    stage_half(srcB, smem + 16384, 1, 0, wid);
    stage_half(srcA, smem,         0, 0, wid);
    stage_half(srcA, smem,         1, 0, wid);
    stage_half(srcB, smem + 49152, 0, 1, wid);
    stage_half(srcB, smem + 49152, 1, 1, wid);
    stage_half(srcA, smem + 32768, 0, 1, wid);
    asm volatile("s_waitcnt vmcnt(6)" ::: "memory");  // tile0's 8 loads done
    MEMCLOB; BAR;

    f32x4 acc[8][4];
    #pragma unroll
    for (int f = 0; f < 8; ++f)
        #pragma unroll
        for (int n = 0; n < 4; ++n)
            acc[f][n] = (f32x4){0.f, 0.f, 0.f, 0.f};

    s16x8 afr[8][2];
    s16x8 bfr[4][2];

    // Pre-loop: tile0's B + c0 reads in flight (12 ds_reads)
    read_b(bfr, smem + 16384, wn, r15, kg);
    read_a_pair<0>(afr, smem, wm, r15, kg);

    for (int t2 = 0; t2 < NT / 2; ++t2) {
        TILE_BODY(0);
        TILE_BODY(1);
    }

    // Epilogue: 16x16 C/D layout col=lane&15, row=(lane>>4)*4+jj [m89-verified]
    // frag f global row = bm*256 + (f>>1)*64 + wm*32 + (f&1)*16 + kg*4 + jj
    float* Cp = C + (size_t)(bm * 256 + wm * 32 + kg * 4) * N_TOT
                  + bn * 256 + wn * 64 + r15;
    #pragma unroll
    for (int f = 0; f < 8; ++f)
        #pragma unroll
        for (int n = 0; n < 4; ++n)
            #pragma unroll
            for (int jj = 0; jj < 4; ++jj) {
                const int roff = (f >> 1) * 64 + (f & 1) * 16 + jj;
                Cp[(size_t)roff * N_TOT + n * 16] = acc[f][n][jj];
            }
}

// ---------------- fallback (only if ws too small) ----------------
#define PAD_ROW 40
__global__ __launch_bounds__(256, 2)
void gemm_rs_fused(const float* __restrict__ A, const float* __restrict__ B,
                   float* __restrict__ C) {
    __shared__ short lA[128 * PAD_ROW];
    __shared__ short lB[128 * PAD_ROW];
    const int bid = blockIdx.x;
    const int sw  = (bid & 7) * (int)(gridDim.x >> 3) + (bid >> 3);
    const int bm = sw >> 5, bn = sw & 31;
    const int tid = threadIdx.x, lane = tid & 63, wid = tid >> 6;
    const int wr = wid >> 1, wc = wid & 1, r15 = lane & 15, kg = lane >> 4;
    const int srow = tid >> 1, scg = tid & 1;
    const float* gA = A + ((size_t)(bm * 128 + srow) << 10) + scg * 16;
    const float* gB = B + ((size_t)(bn * 128 + srow) << 10) + scg * 16;
    short* wpA = lA + srow * PAD_ROW + scg * 16;
    short* wpB = lB + srow * PAD_ROW + scg * 16;
    const short* rpA = lA + (wr * 64 + r15) * PAD_ROW + kg * 8;
    const short* rpB = lB + (wc * 64 + r15) * PAD_ROW + kg * 8;
    f32x4 acc[4][4];
    #pragma unroll
    for (int i = 0; i < 4; ++i)
        #pragma unroll
        for (int j = 0; j < 4; ++j) acc[i][j] = (f32x4){0.f, 0.f, 0.f, 0.f};
    for (int t = 0; t < K_TOT / 32; ++t) {
        const int r = t >> 5, k0 = (t & 31) << 5;
        const float* pA = gA + (size_t)r * (M_TOT * LK) + k0;
        const float* pB = gB + (size_t)r * (N_TOT * LK) + k0;
        f32x4 va[4], vb[4];
        #pragma unroll
        for (int q = 0; q < 4; ++q) va[q] = *(const f32x4*)(pA + q * 4);
        #pragma unroll
        for (int q = 0; q < 4; ++q) vb[q] = *(const f32x4*)(pB + q * 4);
        __syncthreads();
        s16x8 oa0, oa1, ob0, ob1;
        #pragma unroll
        for (int q = 0; q < 2; ++q)
            #pragma unroll
            for (int i = 0; i < 4; ++i) {
                oa0[q * 4 + i] = f2bf(va[q][i]);
                oa1[q * 4 + i] = f2bf(va[q + 2][i]);
                ob0[q * 4 + i] = f2bf(vb[q][i]);
                ob1[q * 4 + i] = f2bf(vb[q + 2][i]);
            }
        *(s16x8*)(wpA) = oa0; *(s16x8*)(wpA + 8) = oa1;
        *(s16x8*)(wpB) = ob0; *(s16x8*)(wpB + 8) = ob1;
        __syncthreads();
        s16x8 af[4], bfr2[4];
        #pragma unroll
        for (int i = 0; i < 4; ++i) af[i]   = *(const s16x8*)(rpA + i * 16 * PAD_ROW);
        #pragma unroll
        for (int i = 0; i < 4; ++i) bfr2[i] = *(const s16x8*)(rpB + i * 16 * PAD_ROW);
        #pragma unroll
        for (int i = 0; i < 4; ++i)
            #pragma unroll
            for (int j = 0; j < 4; ++j)
                acc[i][j] = __builtin_amdgcn_mfma_f32_16x16x32_bf16(
                    af[i], bfr2[j], acc[i][j], 0, 0, 0);
    }
    float* Cp = C + (size_t)(bm * 128 + wr * 64 + kg * 4) * N_TOT
                  + bn * 128 + wc * 64 + r15;
    #pragma unroll
    for (int i = 0; i < 4; ++i)
        #pragma unroll
        for (int j = 0; j < 4; ++j)
            #pragma unroll
            for (int jj = 0; jj < 4; ++jj)
                Cp[(size_t)(i * 16 + jj) * N_TOT + j * 16] = acc[i][j][jj];
}

extern "C" void kernel_launch(void* const* d_in, const int* in_sizes, int n_in,
                              void* d_out, int out_size, void* d_ws, size_t ws_size,
                              hipStream_t stream) {
    const float* A = (const float*)d_in[0];   // [8, 8192, 1024]
    const float* B = (const float*)d_in[1];   // [8, 4096, 1024]
    float* C = (float*)d_out;                 // [8192, 4096]

    const size_t needA = (size_t)M_TOT * K_TOT * 2;
    const size_t needB = (size_t)N_TOT * K_TOT * 2;

    if (ws_size >= needA + needB) {
        short* Abf = (short*)d_ws;
        short* Bbf = (short*)((char*)d_ws + needA);
        cvt_bf16<<<dim3(NR * M_TOT / 2), dim3(256), 0, stream>>>(A, Abf, 13, 8191);
        cvt_bf16<<<dim3(NR * N_TOT / 2), dim3(256), 0, stream>>>(B, Bbf, 12, 4095);
        gemm8<<<dim3((M_TOT / 256) * (N_TOT / 256)), dim3(512), 131072, stream>>>(Abf, Bbf, C);
    } else {
        gemm_rs_fused<<<dim3((M_TOT / 128) * (N_TOT / 128)), dim3(256), 0, stream>>>(A, B, C);
    }
}

// Round 6
// 516.984 us; speedup vs baseline: 2.4128x; 1.0123x over previous
//
#include <hip/hip_runtime.h>
#include <hip/hip_bf16.h>

// C[m,n] = sum_{r,k} A[r][m][k] * B[r][n][k]
// Phase 1: convert A,B -> bf16 in d_ws (K contiguous: k' = r*1024+k).
// Phase 2: 256x256 GEMM, 16x16x32 MFMA, one-cluster-ahead ds_read pipeline,
//          counted lgkmcnt + counted vmcnt, T2 swizzle, T5 setprio.
// r5->r6: p4's 12-read burst (B + c0 of next tile) was issued AFTER mfma3
//         inside the barrier pair -> ~750 cy/tile LDS-only bubble. Now:
//         stage + c0' reads issue first, then {mfma-group-n ; read bfr[n]'}
//         fine-grained interleave (per-fragment WAR keeps reg growth ~8).

#define M_TOT 8192
#define N_TOT 4096
#define LK    1024
#define NR    8
#define K_TOT (NR * LK)    // 8192
#define NT    (K_TOT / 64) // 128 K-tiles

typedef float f32x4 __attribute__((ext_vector_type(4)));
typedef short s16x8 __attribute__((ext_vector_type(8)));
typedef const __attribute__((address_space(1))) unsigned int* gptr_t;
typedef __attribute__((address_space(3))) unsigned int* lptr_t;

__device__ inline short f2bf(float f) {
    __hip_bfloat16 h = __float2bfloat16(f);
    return *reinterpret_cast<short*>(&h);
}

// ---------------- convert pre-pass ----------------
__global__ __launch_bounds__(256)
void cvt_bf16(const float* __restrict__ in, short* __restrict__ out,
              int row_shift, int row_mask) {
    const int row = blockIdx.x * 2 + (threadIdx.x >> 7);
    const int c   = (threadIdx.x & 127) * 8;
    const int r   = row >> row_shift;
    const int m   = row & row_mask;
    const float* src = in + ((size_t)row << 10) + c;
    f32x4 v0 = *(const f32x4*)src;
    f32x4 v1 = *(const f32x4*)(src + 4);
    s16x8 o;
    #pragma unroll
    for (int j = 0; j < 4; ++j) { o[j] = f2bf(v0[j]); o[j + 4] = f2bf(v1[j]); }
    *(s16x8*)(out + ((size_t)m << 13) + ((size_t)r << 10) + c) = o;
}

// ---------------- GEMM helpers ----------------
// LDS: buf P at P*32768 shorts; A-tile [256][64] at +0, B-tile at +16384.
// Swizzle: LDS granule g of row r holds global granule g ^ (r&7).

__device__ __forceinline__ void stage_half(const short* srcBase, short* ldsOp,
                                           int half, int ktile, int wid) {
    #pragma unroll
    for (int q = 0; q < 2; ++q) {
        const short* src = srcBase + (size_t)(half * 128 + q * 8) * K_TOT + ktile * 64;
        short* dst = ldsOp + (half * 128 + wid * 16 + q * 8) * 64;  // wave-uniform
        __builtin_amdgcn_global_load_lds((gptr_t)src, (lptr_t)dst, 16, 0, 0);
    }
}

// A cluster C: frags f=2C,2C+1 at rows C*64 + wm*32 + {0,16} + r15
template<int C>
__device__ __forceinline__ void read_a_pair(s16x8 (&afr)[8][2], const short* lAc,
                                            int wm, int r15, int kg) {
    #pragma unroll
    for (int fo = 0; fo < 2; ++fo)
        #pragma unroll
        for (int ks = 0; ks < 2; ++ks) {
            const int row = C * 64 + wm * 32 + fo * 16 + r15;
            const int off = row * 64 + ((((ks << 2) | kg) ^ (row & 7)) << 3);
            afr[C * 2 + fo][ks] = *(const s16x8*)(lAc + off);
        }
}

__device__ __forceinline__ void read_b(s16x8 (&bfr)[4][2], const short* lBc,
                                       int wn, int r15, int kg) {
    #pragma unroll
    for (int n = 0; n < 4; ++n)
        #pragma unroll
        for (int ks = 0; ks < 2; ++ks) {
            const int row = wn * 64 + n * 16 + r15;
            const int off = row * 64 + ((((ks << 2) | kg) ^ (row & 7)) << 3);
            bfr[n][ks] = *(const s16x8*)(lBc + off);
        }
}

template<int N>
__device__ __forceinline__ void read_b_one(s16x8 (&bfr)[4][2], const short* lBc,
                                           int wn, int r15, int kg) {
    #pragma unroll
    for (int ks = 0; ks < 2; ++ks) {
        const int row = wn * 64 + N * 16 + r15;
        const int off = row * 64 + ((((ks << 2) | kg) ^ (row & 7)) << 3);
        bfr[N][ks] = *(const s16x8*)(lBc + off);
    }
}

template<int Q>
__device__ __forceinline__ void mfma_quad(f32x4 (&acc)[8][4], s16x8 (&afr)[8][2],
                                          s16x8 (&bfr)[4][2]) {
    __builtin_amdgcn_s_setprio(1);
    #pragma unroll
    for (int fo = 0; fo < 2; ++fo)
        #pragma unroll
        for (int n = 0; n < 4; ++n)
            #pragma unroll
            for (int ks = 0; ks < 2; ++ks)
                acc[Q * 2 + fo][n] = __builtin_amdgcn_mfma_f32_16x16x32_bf16(
                    afr[Q * 2 + fo][ks], bfr[n][ks], acc[Q * 2 + fo][n], 0, 0, 0);
    __builtin_amdgcn_s_setprio(0);
}

// mfma group for cluster 3, single B-fragment N (used in the p4 interleave)
template<int N>
__device__ __forceinline__ void mfma_n3(f32x4 (&acc)[8][4], s16x8 (&afr)[8][2],
                                        s16x8 (&bfr)[4][2]) {
    #pragma unroll
    for (int fo = 0; fo < 2; ++fo)
        #pragma unroll
        for (int ks = 0; ks < 2; ++ks)
            acc[6 + fo][N] = __builtin_amdgcn_mfma_f32_16x16x32_bf16(
                afr[6 + fo][ks], bfr[N][ks], acc[6 + fo][N], 0, 0, 0);
}

#define MEMCLOB asm volatile("" ::: "memory")
#define BAR     __builtin_amdgcn_s_barrier()
#define SCHED0  __builtin_amdgcn_sched_barrier(0)

// One K-tile, parity P. Entering p1: next-tile B + c0 reads in flight
// (issued inside previous p4's interleave).
#define TILE_BODY(P) do {                                                     \
    const int t = 2 * t2 + (P);                                               \
    const short* lAc = smem + ((P) << 15);                                    \
    short* bufN = smem + (((P) ^ 1) << 15);                                   \
    short* bufC = smem + ((P) << 15);                                         \
    /* p1: issue c1; stage A1(t+1). mfma0 needs afr01'+bfr' (12 oldest). */   \
    read_a_pair<1>(afr, lAc, wm, r15, kg);                                    \
    if (t + 1 < NT) stage_half(srcA, bufN, 1, t + 1, wid);                    \
    MEMCLOB; BAR;                                                             \
    asm volatile("s_waitcnt lgkmcnt(4)" ::: "memory"); SCHED0;                \
    mfma_quad<0>(acc, afr, bfr);                                              \
    MEMCLOB; BAR;                                                             \
    /* p2: issue c2; stage B0(t+2) (current-B reads drained at p1's wait) */  \
    read_a_pair<2>(afr, lAc, wm, r15, kg);                                    \
    if (t + 2 < NT) stage_half(srcB, bufC + 16384, 0, t + 2, wid);            \
    MEMCLOB; BAR;                                                             \
    asm volatile("s_waitcnt lgkmcnt(4)" ::: "memory"); SCHED0;                \
    mfma_quad<1>(acc, afr, bfr);                                              \
    MEMCLOB; BAR;                                                             \
    /* p3: issue c3; stage B1(t+2) */                                         \
    read_a_pair<3>(afr, lAc, wm, r15, kg);                                    \
    if (t + 2 < NT) stage_half(srcB, bufC + 16384, 1, t + 2, wid);            \
    MEMCLOB; BAR;                                                             \
    asm volatile("s_waitcnt lgkmcnt(4)" ::: "memory"); SCHED0;                \
    mfma_quad<2>(acc, afr, bfr);                                              \
    MEMCLOB; BAR;                                                             \
    /* p4: counted vmcnt proves tile t+1 staged (cross-wave via BAR).        */\
    /* Then: stage A0(t+2) early (writes bufC-A rows 0-127; only c3 rows    */\
    /* 192-255 can be outstanding cross-wave -> disjoint), read c0' from    */\
    /* bufN, drain c3 (counted), then {mfma-group-n ; read bfr[n]'}         */\
    /* interleave so LDS reads hide under MFMA issue.                        */\
    if (t < NT - 2)       asm volatile("s_waitcnt vmcnt(4)" ::: "memory");    \
    else if (t == NT - 2) asm volatile("s_waitcnt vmcnt(0)" ::: "memory");    \
    MEMCLOB; BAR;                                                             \
    if (t + 2 < NT) stage_half(srcA, bufC, 0, t + 2, wid);                    \
    if (t + 1 < NT) {                                                         \
        read_a_pair<0>(afr, bufN, wm, r15, kg);                               \
        asm volatile("s_waitcnt lgkmcnt(4)" ::: "memory"); SCHED0;            \
        __builtin_amdgcn_s_setprio(1);                                        \
        mfma_n3<0>(acc, afr, bfr);                                            \
        read_b_one<0>(bfr, bufN + 16384, wn, r15, kg);                        \
        mfma_n3<1>(acc, afr, bfr);                                            \
        read_b_one<1>(bfr, bufN + 16384, wn, r15, kg);                        \
        mfma_n3<2>(acc, afr, bfr);                                            \
        read_b_one<2>(bfr, bufN + 16384, wn, r15, kg);                        \
        mfma_n3<3>(acc, afr, bfr);                                            \
        read_b_one<3>(bfr, bufN + 16384, wn, r15, kg);                        \
        __builtin_amdgcn_s_setprio(0);                                        \
    } else {                                                                  \
        asm volatile("s_waitcnt lgkmcnt(0)" ::: "memory"); SCHED0;            \
        __builtin_amdgcn_s_setprio(1);                                        \
        mfma_n3<0>(acc, afr, bfr);                                            \
        mfma_n3<1>(acc, afr, bfr);                                            \
        mfma_n3<2>(acc, afr, bfr);                                            \
        mfma_n3<3>(acc, afr, bfr);                                            \
        __builtin_amdgcn_s_setprio(0);                                        \
    }                                                                         \
    MEMCLOB; BAR;                                                             \
} while (0)

__global__ __launch_bounds__(512, 2)
void gemm8(const short* __restrict__ A, const short* __restrict__ B,
           float* __restrict__ C) {
    extern __shared__ short smem[];

    const int tid  = threadIdx.x;
    const int lane = tid & 63;
    const int wid  = tid >> 6;
    const int wm   = wid >> 2;      // 0..1
    const int wn   = wid & 3;       // 0..3
    const int r15  = lane & 15;
    const int kg   = lane >> 4;     // 0..3
    const int l8   = lane >> 3;     // 0..7
    const int g16  = (lane & 7) ^ l8;  // pre-swizzled source granule

    const int bid = blockIdx.x;
    const int sw  = (bid & 7) * 64 + (bid >> 3);   // bijective (512 % 8 == 0)
    const int bm  = sw >> 4;   // 0..31
    const int bn  = sw & 15;   // 0..15

    const short* srcA = A + (size_t)(bm * 256 + wid * 16 + l8) * K_TOT + g16 * 8;
    const short* srcB = B + (size_t)(bn * 256 + wid * 16 + l8) * K_TOT + g16 * 8;

    // Prologue: tile0 complete + tile1 {B0,B1,A0} = 14 load instrs.
    stage_half(srcB, smem + 16384, 0, 0, wid);
    stage_half(srcB, smem + 16384, 1, 0, wid);
    stage_half(srcA, smem,         0, 0, wid);
    stage_half(srcA, smem,         1, 0, wid);
    stage_half(srcB, smem + 49152, 0, 1, wid);
    stage_half(srcB, smem + 49152, 1, 1, wid);
    stage_half(srcA, smem + 32768, 0, 1, wid);
    asm volatile("s_waitcnt vmcnt(6)" ::: "memory");  // tile0's 8 loads done
    MEMCLOB; BAR;

    f32x4 acc[8][4];
    #pragma unroll
    for (int f = 0; f < 8; ++f)
        #pragma unroll
        for (int n = 0; n < 4; ++n)
            acc[f][n] = (f32x4){0.f, 0.f, 0.f, 0.f};

    s16x8 afr[8][2];
    s16x8 bfr[4][2];

    // Pre-loop: tile0's B + c0 reads in flight (12 ds_reads)
    read_b(bfr, smem + 16384, wn, r15, kg);
    read_a_pair<0>(afr, smem, wm, r15, kg);

    for (int t2 = 0; t2 < NT / 2; ++t2) {
        TILE_BODY(0);
        TILE_BODY(1);
    }

    // Epilogue: 16x16 C/D layout col=lane&15, row=(lane>>4)*4+jj [m89-verified]
    float* Cp = C + (size_t)(bm * 256 + wm * 32 + kg * 4) * N_TOT
                  + bn * 256 + wn * 64 + r15;
    #pragma unroll
    for (int f = 0; f < 8; ++f)
        #pragma unroll
        for (int n = 0; n < 4; ++n)
            #pragma unroll
            for (int jj = 0; jj < 4; ++jj) {
                const int roff = (f >> 1) * 64 + (f & 1) * 16 + jj;
                Cp[(size_t)roff * N_TOT + n * 16] = acc[f][n][jj];
            }
}

// ---------------- fallback (only if ws too small) ----------------
#define PAD_ROW 40
__global__ __launch_bounds__(256, 2)
void gemm_rs_fused(const float* __restrict__ A, const float* __restrict__ B,
                   float* __restrict__ C) {
    __shared__ short lA[128 * PAD_ROW];
    __shared__ short lB[128 * PAD_ROW];
    const int bid = blockIdx.x;
    const int sw  = (bid & 7) * (int)(gridDim.x >> 3) + (bid >> 3);
    const int bm = sw >> 5, bn = sw & 31;
    const int tid = threadIdx.x, lane = tid & 63, wid = tid >> 6;
    const int wr = wid >> 1, wc = wid & 1, r15 = lane & 15, kg = lane >> 4;
    const int srow = tid >> 1, scg = tid & 1;
    const float* gA = A + ((size_t)(bm * 128 + srow) << 10) + scg * 16;
    const float* gB = B + ((size_t)(bn * 128 + srow) << 10) + scg * 16;
    short* wpA = lA + srow * PAD_ROW + scg * 16;
    short* wpB = lB + srow * PAD_ROW + scg * 16;
    const short* rpA = lA + (wr * 64 + r15) * PAD_ROW + kg * 8;
    const short* rpB = lB + (wc * 64 + r15) * PAD_ROW + kg * 8;
    f32x4 acc[4][4];
    #pragma unroll
    for (int i = 0; i < 4; ++i)
        #pragma unroll
        for (int j = 0; j < 4; ++j) acc[i][j] = (f32x4){0.f, 0.f, 0.f, 0.f};
    for (int t = 0; t < K_TOT / 32; ++t) {
        const int r = t >> 5, k0 = (t & 31) << 5;
        const float* pA = gA + (size_t)r * (M_TOT * LK) + k0;
        const float* pB = gB + (size_t)r * (N_TOT * LK) + k0;
        f32x4 va[4], vb[4];
        #pragma unroll
        for (int q = 0; q < 4; ++q) va[q] = *(const f32x4*)(pA + q * 4);
        #pragma unroll
        for (int q = 0; q < 4; ++q) vb[q] = *(const f32x4*)(pB + q * 4);
        __syncthreads();
        s16x8 oa0, oa1, ob0, ob1;
        #pragma unroll
        for (int q = 0; q < 2; ++q)
            #pragma unroll
            for (int i = 0; i < 4; ++i) {
                oa0[q * 4 + i] = f2bf(va[q][i]);
                oa1[q * 4 + i] = f2bf(va[q + 2][i]);
                ob0[q * 4 + i] = f2bf(vb[q][i]);
                ob1[q * 4 + i] = f2bf(vb[q + 2][i]);
            }
        *(s16x8*)(wpA) = oa0; *(s16x8*)(wpA + 8) = oa1;
        *(s16x8*)(wpB) = ob0; *(s16x8*)(wpB + 8) = ob1;
        __syncthreads();
        s16x8 af[4], bfr2[4];
        #pragma unroll
        for (int i = 0; i < 4; ++i) af[i]   = *(const s16x8*)(rpA + i * 16 * PAD_ROW);
        #pragma unroll
        for (int i = 0; i < 4; ++i) bfr2[i] = *(const s16x8*)(rpB + i * 16 * PAD_ROW);
        #pragma unroll
        for (int i = 0; i < 4; ++i)
            #pragma unroll
            for (int j = 0; j < 4; ++j)
                acc[i][j] = __builtin_amdgcn_mfma_f32_16x16x32_bf16(
                    af[i], bfr2[j], acc[i][j], 0, 0, 0);
    }
    float* Cp = C + (size_t)(bm * 128 + wr * 64 + kg * 4) * N_TOT
                  + bn * 128 + wc * 64 + r15;
    #pragma unroll
    for (int i = 0; i < 4; ++i)
        #pragma unroll
        for (int j = 0; j < 4; ++j)
            #pragma unroll
            for (int jj = 0; jj < 4; ++jj)
                Cp[(size_t)(i * 16 + jj) * N_TOT + j * 16] = acc[i][j][jj];
}

extern "C" void kernel_launch(void* const* d_in, const int* in_sizes, int n_in,
                              void* d_out, int out_size, void* d_ws, size_t ws_size,
                              hipStream_t stream) {
    const float* A = (const float*)d_in[0];   // [8, 8192, 1024]
    const float* B = (const float*)d_in[1];   // [8, 4096, 1024]
    float* C = (float*)d_out;                 // [8192, 4096]

    const size_t needA = (size_t)M_TOT * K_TOT * 2;
    const size_t needB = (size_t)N_TOT * K_TOT * 2;

    if (ws_size >= needA + needB) {
        short* Abf = (short*)d_ws;
        short* Bbf = (short*)((char*)d_ws + needA);
        cvt_bf16<<<dim3(NR * M_TOT / 2), dim3(256), 0, stream>>>(A, Abf, 13, 8191);
        cvt_bf16<<<dim3(NR * N_TOT / 2), dim3(256), 0, stream>>>(B, Bbf, 12, 4095);
        gemm8<<<dim3((M_TOT / 256) * (N_TOT / 256)), dim3(512), 131072, stream>>>(Abf, Bbf, C);
    } else {
        gemm_rs_fused<<<dim3((M_TOT / 128) * (N_TOT / 128)), dim3(256), 0, stream>>>(A, B, C);
    }
}